// Round 5
// baseline (319.562 us; speedup 1.0000x reference)
//
#include <hip/hip_runtime.h>

#define DEVI __device__ __forceinline__

typedef unsigned short u16;
typedef unsigned int   u32;
typedef __attribute__((ext_vector_type(4))) float f32x4;
typedef __attribute__((ext_vector_type(8))) short short8;
typedef __attribute__((ext_vector_type(8))) __bf16 bf16x8;

#define B_   2
#define S_   2048
#define H_   2048
#define NH_  16
#define HD_  128
#define BH_  (B_*NH_)
// 1/sqrt(128) * log2(e)  -> scores land in log2 domain, softmax uses exp2
#define QSCALE 0.12751743f

DEVI u16 f2b(float f){                       // f32 -> bf16 bits, RNE
  u32 u = __builtin_bit_cast(u32, f);
  u32 r = (u + 0x7fffu + ((u >> 16) & 1u)) >> 16;
  return (u16)r;
}
DEVI float b2f(u16 h){
  u32 u = ((u32)h) << 16;
  return __builtin_bit_cast(float, u);
}
DEVI u32 cvt_pk_bf16(float lo, float hi){    // word = {lo: bf16(lo), hi: bf16(hi)}
  u32 r; asm("v_cvt_pk_bf16_f32 %0, %1, %2" : "=v"(r) : "v"(lo), "v"(hi)); return r;
}
DEVI f32x4 mfma_bf16(short8 a, short8 b, f32x4 c){
  return __builtin_amdgcn_mfma_f32_16x16x32_bf16(
      __builtin_bit_cast(bf16x8, a), __builtin_bit_cast(bf16x8, b), c, 0, 0, 0);
}
DEVI void gl_lds16(const void* g, void* l){
  __builtin_amdgcn_global_load_lds((const __attribute__((address_space(1))) void*)g,
                                   (__attribute__((address_space(3))) void*)l, 16, 0, 0);
}

// Precompute per-thread swizzled source pointers for a 16KB-tile stage
// (1024 x 16B chunks; LOG2CPR = log2(chunks per row)). Source column is
// XOR-swizzled, LDS dest stays linear (read side applies the same XOR).
template<int LOG2CPR>
DEVI void stage_ptrs(const u16* src, int srcStride, int tid, const u16* p[4]){
#pragma unroll
  for (int i = 0; i < 4; ++i){
    int lin = i*256 + tid;
    int row = lin >> LOG2CPR;
    int cb  = ((lin & ((1 << LOG2CPR) - 1)) * 16) ^ ((row & 7) << 4);
    p[i] = src + (size_t)row * srcStride + (cb >> 1);
  }
}

// ---------------- fused f32 -> bf16 convert (x, wq, wk, wv, wo) ----------------
__global__ __launch_bounds__(256) void cvt5_kernel(
    const float* __restrict__ x,  const float* __restrict__ wq,
    const float* __restrict__ wk, const float* __restrict__ wv,
    const float* __restrict__ wo, u16* __restrict__ xb,
    u16* __restrict__ wqkv, u16* __restrict__ wob){
  int i = blockIdx.x * 256 + threadIdx.x;          // [0, 6291456)
  const float* src; u16* dst; int off;
  if      (i < 2097152){ src = x;  dst = xb;             off = i;           }
  else if (i < 3145728){ src = wq; dst = wqkv;           off = i - 2097152; }
  else if (i < 4194304){ src = wk; dst = wqkv + 4194304; off = i - 3145728; }
  else if (i < 5242880){ src = wv; dst = wqkv + 8388608; off = i - 4194304; }
  else                 { src = wo; dst = wob;            off = i - 5242880; }
  float4 v = ((const float4*)src)[off];
  uint2 o;
  o.x = (u32)f2b(v.x) | ((u32)f2b(v.y) << 16);
  o.y = (u32)f2b(v.z) | ((u32)f2b(v.w) << 16);
  ((uint2*)dst)[off] = o;
}

// ---------------- GEMM C = A * B^T  (A [M][K] bf16 rm, Bw [N][K] bf16 rm) ----------------
// 128x128 tile, BK=64, 4 waves (2x2, each 64x64), mfma 16x16x32 bf16.
// EPI 0: write f32 to C [M][N].
// EPI 1: fused RoPE (Q scaled by QSCALE) + scatter bf16 into Q/K/V [B,NH,S,HD].
template<int EPI>
__global__ __launch_bounds__(256) void gemm_bt(
    const u16* __restrict__ A, const u16* __restrict__ Bw,
    float* __restrict__ C, u16* __restrict__ Qd, u16* __restrict__ Kd, u16* __restrict__ Vd,
    const float* __restrict__ F, int M, int N, int K)
{
  __shared__ __align__(16) u16 As[128*64];
  __shared__ __align__(16) u16 Bs[128*64];
  const int tid  = threadIdx.x, lane = tid & 63, wid = tid >> 6;
  const int wr   = wid >> 1, wc = wid & 1;
  const int lrow = lane & 15, lk = lane >> 4;
  const int RB = blockIdx.y * 128, CB = blockIdx.x * 128;
  f32x4 acc[4][4] = {};

  // staging pointers: computed once, advanced by +64 elems per K-step
  const u16* asrc[4]; const u16* bsrc[4];
  stage_ptrs<3>(A  + (size_t)RB * K, K, tid, asrc);
  stage_ptrs<3>(Bw + (size_t)CB * K, K, tid, bsrc);
  u16* const adst = &As[(size_t)(tid >> 6) * 512];   // wave-uniform +lane*16B by HW
  u16* const bdst = &Bs[(size_t)(tid >> 6) * 512];

  for (int k0 = 0; k0 < K; k0 += 64){
    __syncthreads();
#pragma unroll
    for (int i = 0; i < 4; ++i){
      gl_lds16(asrc[i], adst + i*2048); asrc[i] += 64;
      gl_lds16(bsrc[i], bdst + i*2048); bsrc[i] += 64;
    }
    __syncthreads();
#pragma unroll
    for (int kk = 0; kk < 2; ++kk){
      short8 af[4], bf[4];
#pragma unroll
      for (int m = 0; m < 4; ++m){
        int row = wr*64 + m*16 + lrow;
        int cb  = (kk*64 + lk*16) ^ ((row & 7) << 4);
        af[m] = *(const short8*)&As[row*64 + (cb >> 1)];
      }
#pragma unroll
      for (int n = 0; n < 4; ++n){
        int row = wc*64 + n*16 + lrow;
        int cb  = (kk*64 + lk*16) ^ ((row & 7) << 4);
        bf[n] = *(const short8*)&Bs[row*64 + (cb >> 1)];
      }
#pragma unroll
      for (int m = 0; m < 4; ++m)
#pragma unroll
        for (int n = 0; n < 4; ++n)
          acc[m][n] = mfma_bf16(af[m], bf[n], acc[m][n]);
    }
  }

#pragma unroll
  for (int m = 0; m < 4; ++m){
#pragma unroll
    for (int n = 0; n < 4; ++n){
      const int col = CB + wc*64 + n*16 + lrow;
#pragma unroll
      for (int r = 0; r < 4; ++r){
        const int row = RB + wr*64 + m*16 + lk*4 + r;
        float v = acc[m][n][r];
        if constexpr (EPI == 0){
          C[(size_t)row * N + col] = v;
        } else {
          const int which = col >> 11;
          const int hd = col & 2047;
          const int h = hd >> 7, d = hd & 127;
          const int b = row >> 11, s = row & 2047;
          if (which <= 1){               // fused RoPE on Q and K (f32, pre-round)
            float p = __shfl_xor(v, 1);  // partner element of the (even,odd) pair
            float2 f = *(const float2*)&F[(size_t)s*128 + (d & ~1)];
            v = (d & 1) ? (v*f.x + p*f.y) : (v*f.x - p*f.y);
            if (which == 0) v *= QSCALE;
          }
          u16* dst = (which == 0) ? Qd : (which == 1) ? Kd : Vd;
          dst[(((size_t)(b*NH_ + h)) * S_ + s) * HD_ + d] = f2b(v);
        }
      }
    }
  }
}

// ---------------- V transpose: [BH,S,HD] -> [BH,HD,S] ----------------
__global__ void transpose_v(const u16* __restrict__ V, u16* __restrict__ Vt){
  __shared__ u16 t[32][33];
  int s0 = blockIdx.x * 32, d0 = blockIdx.y * 32, bh = blockIdx.z;
  const u16* vb = V  + (size_t)bh * S_ * HD_;
  u16*       tb = Vt + (size_t)bh * HD_ * S_;
  int tx = threadIdx.x, ty = threadIdx.y;
#pragma unroll
  for (int i = 0; i < 4; ++i)
    t[ty + i*8][tx] = vb[(size_t)(s0 + ty + i*8) * HD_ + d0 + tx];
  __syncthreads();
#pragma unroll
  for (int i = 0; i < 4; ++i)
    tb[(size_t)(d0 + ty + i*8) * S_ + s0 + tx] = t[tx][ty + i*8];
}

// ---------------- Flash attention (causal), pair-balanced ----------------
// Each block handles TWO complementary q-stripes of 128 rows: qb_hi = 15-x (first,
// long) then qb_lo = x (short, K/V prefix L2-warm). 34 kv-tiles per block, uniform.
// Per stripe: 4 waves x 32 q rows, KVBLK=64, double-buffered K/V via global_load_lds.
// Swapped QK^T: S^T[kv][q] = mfma(A=K, B=Q)  -> per-lane softmax (q = lane&15).
// Flipped PV:   O^T[d][q]  = mfma(A=V^T, B=P) -> no cross-lane rescale/normalize.
// Scores in log2 domain (log2e folded into fused-RoPE Q scale); softmax = exp2.
__global__ __launch_bounds__(256) void attn_kernel(
    const u16* __restrict__ Q, const u16* __restrict__ K, const u16* __restrict__ Vt,
    u16* __restrict__ O)
{
  __shared__ __align__(16) u16 Ks[2][64*128];  // [kv][d], swizzled    32 KB
  __shared__ __align__(16) u16 Vs[2][128*64];  // [d][kv], swizzled    32 KB
  __shared__ __align__(16) u16 Ps[4][32*64];   // per-wave P [32q][64kv], XOR-swz  16 KB
  const int tid  = threadIdx.x, lane = tid & 63, wid = tid >> 6;
  const int lrow = lane & 15, lk = lane >> 4;

  // XCD-locality swizzle: lin%8 = XCD (heuristic); bh ≡ XCD (mod 8) ->
  // 4 distinct bh per XCD -> K/V working set ~4MB = one L2.
  const int lin = blockIdx.x;
  const int bh  = (lin & 7) + ((lin >> 6) << 3);
  const int x   = (lin >> 3) & 7;

  const u16* Kb  = K  + (size_t)bh * S_ * HD_;
  const u16* Vtb = Vt + (size_t)bh * HD_ * S_;
  const int b = bh >> 4, h = bh & 15;

  u16* const kld = &Ks[0][(size_t)wid * 512];   // wave-uniform LDS dests (buf 0)
  u16* const vld = &Vs[0][(size_t)wid * 512];
  const int bufstep = 64*128;                   // elems between buf0 and buf1

  for (int pass = 0; pass < 2; ++pass){
    const int qb = pass ? x : (15 - x);
    const int q0 = qb * 128;
    const int ntile = q0/64 + 2;
    const int qwmax = q0 + wid*32 + 31;         // this wave's max q row

    // Q fragments (B-operand): col q = q0 + wid*32 + m*16 + lrow, k = kc*32+lk*8+j
    short8 qf[2][4];
#pragma unroll
    for (int m = 0; m < 2; ++m){
      const u16* qb_ = Q + ((size_t)bh * S_ + q0 + wid*32 + m*16 + lrow) * HD_;
#pragma unroll
      for (int kc = 0; kc < 4; ++kc) qf[m][kc] = *(const short8*)&qb_[kc*32 + lk*8];
    }

    // staging pointers: computed once per pass, advanced per staged tile
    const u16* kp[4]; const u16* vp[4];
    stage_ptrs<4>(Kb,  HD_, tid, kp);
    stage_ptrs<3>(Vtb, S_,  tid, vp);

    f32x4 acco[2][8] = {};
    float m_[2] = {-3.0e38f, -3.0e38f}, l_[2] = {0.0f, 0.0f};

    int cur = 0;
#pragma unroll
    for (int i = 0; i < 4; ++i){
      gl_lds16(kp[i], kld + i*2048); kp[i] += 64*HD_;
      gl_lds16(vp[i], vld + i*2048); vp[i] += 64;
    }
    __syncthreads();

    for (int t = 0; t < ntile; ++t){
      if (t + 1 < ntile){                      // issue next-tile stage; flies under compute
        const int bo = (cur^1) * bufstep;
#pragma unroll
        for (int i = 0; i < 4; ++i){
          gl_lds16(kp[i], kld + bo + i*2048); kp[i] += 64*HD_;
          gl_lds16(vp[i], vld + bo + i*2048); vp[i] += 64;
        }
      }
      const int kv0 = t*64;
      if (kv0 <= qwmax){                       // skip fully-masked tiles for this wave
        const u16* ks = &Ks[cur][0];
        const u16* vs = &Vs[cur][0];

        // ---- QK^T (swapped): sc[m][nt] = S^T[kv][q] ----
        f32x4 sc[2][4] = {};
        __builtin_amdgcn_s_setprio(1);
#pragma unroll
        for (int nt = 0; nt < 4; ++nt){
          int row = nt*16 + lrow;
#pragma unroll
          for (int kc = 0; kc < 4; ++kc){
            int cb = (kc*64 + lk*16) ^ ((row & 7) << 4);
            short8 kf = *(const short8*)&ks[row*128 + (cb >> 1)];
            sc[0][nt] = mfma_bf16(kf, qf[0][kc], sc[0][nt]);
            sc[1][nt] = mfma_bf16(kf, qf[1][kc], sc[1][nt]);
          }
        }
        __builtin_amdgcn_s_setprio(0);

        if (t >= ntile - 2){   // diagonal region: causal mask
#pragma unroll
          for (int m = 0; m < 2; ++m){
            int qg = q0 + wid*32 + m*16 + lrow;
#pragma unroll
            for (int nt = 0; nt < 4; ++nt)
#pragma unroll
              for (int r = 0; r < 4; ++r)
                if (kv0 + nt*16 + lk*4 + r > qg) sc[m][nt][r] = -1.0e30f;
          }
        }

        // ---- per-lane online softmax (exp2 domain) + P pack/store ----
        u16* pw = &Ps[wid][0];
#pragma unroll
        for (int m = 0; m < 2; ++m){
          float pmax = sc[m][0][0];
#pragma unroll
          for (int nt = 0; nt < 4; ++nt)
#pragma unroll
            for (int r = 0; r < 4; ++r) pmax = fmaxf(pmax, sc[m][nt][r]);
          pmax = fmaxf(pmax, __shfl_xor(pmax, 16));
          pmax = fmaxf(pmax, __shfl_xor(pmax, 32));
          if (!__all(pmax - m_[m] <= 11.0f)){       // defer-max (log2-domain THR)
            float mn = fmaxf(m_[m], pmax);
            float c = exp2f(m_[m] - mn);
            l_[m] *= c;
#pragma unroll
            for (int dt = 0; dt < 8; ++dt)
#pragma unroll
              for (int r = 0; r < 4; ++r) acco[m][dt][r] *= c;
            m_[m] = mn;
          }
          float rs = 0.0f;
#pragma unroll
          for (int nt = 0; nt < 4; ++nt)
#pragma unroll
            for (int r = 0; r < 4; ++r){
              float p = exp2f(sc[m][nt][r] - m_[m]);
              sc[m][nt][r] = p;
              rs += p;
            }
          rs += __shfl_xor(rs, 16);
          rs += __shfl_xor(rs, 32);
          l_[m] += rs;
          int qrow = m*16 + lrow;
#pragma unroll
          for (int nt = 0; nt < 4; ++nt){
            uint2 wv;
            wv.x = cvt_pk_bf16(sc[m][nt][0], sc[m][nt][1]);
            wv.y = cvt_pk_bf16(sc[m][nt][2], sc[m][nt][3]);
            int boff = (nt*32 + lk*8) ^ ((qrow & 7) << 4);
            *(uint2*)((char*)&pw[qrow*64] + boff) = wv;
          }
        }

        // ---- PV (flipped): acco[m][dt] += V^T x P ----
#pragma unroll
        for (int kc2 = 0; kc2 < 2; ++kc2){
          short8 pf[2];
#pragma unroll
          for (int m = 0; m < 2; ++m){
            int qrow = m*16 + lrow;
            int boff = (kc2*64 + lk*16) ^ ((qrow & 7) << 4);
            pf[m] = *(const short8*)((const char*)&pw[qrow*64] + boff);
          }
          __builtin_amdgcn_s_setprio(1);
#pragma unroll
          for (int dt = 0; dt < 8; ++dt){
            int row = dt*16 + lrow;
            int cb = (kc2*64 + lk*16) ^ ((row & 7) << 4);
            short8 vf = *(const short8*)&vs[row*64 + (cb >> 1)];
            acco[0][dt] = mfma_bf16(vf, pf[0], acco[0][dt]);
            acco[1][dt] = mfma_bf16(vf, pf[1], acco[1][dt]);
          }
          __builtin_amdgcn_s_setprio(0);
        }
      }

      __syncthreads();     // drains vmcnt(0): staged loads had the whole tile to land
      cur ^= 1;
    }

    // ---- epilogue: normalize + packed store ----
#pragma unroll
    for (int m = 0; m < 2; ++m){
      float inv = 1.0f / l_[m];
      int qg = q0 + wid*32 + m*16 + lrow;
      u16* ob = O + ((size_t)(b*S_ + qg)) * H_ + h*128;
#pragma unroll
      for (int dt = 0; dt < 8; ++dt){
        uint2 wv;
        wv.x = cvt_pk_bf16(acco[m][dt][0]*inv, acco[m][dt][1]*inv);
        wv.y = cvt_pk_bf16(acco[m][dt][2]*inv, acco[m][dt][3]*inv);
        *(uint2*)&ob[dt*16 + lk*4] = wv;
      }
    }
    __syncthreads();       // pass boundary: LDS reuse safe
  }
}

// ---------------- launch ----------------
extern "C" void kernel_launch(void* const* d_in, const int* in_sizes, int n_in,
                              void* d_out, int out_size, void* d_ws, size_t ws_size,
                              hipStream_t stream)
{
  (void)in_sizes; (void)n_in; (void)out_size; (void)ws_size;
  const float* x  = (const float*)d_in[0];
  const float* fc = (const float*)d_in[1];   // freqs_cis [S,64,2]
  const float* wq = (const float*)d_in[3];
  const float* wk = (const float*)d_in[4];
  const float* wv = (const float*)d_in[5];
  const float* wo = (const float*)d_in[6];

  char* w = (char*)d_ws;
  u16* xb   = (u16*)(w);                 // [4096,2048] bf16
  u16* wqkv = (u16*)(w + 16777216);      // [6144,2048] bf16
  u16* wob  = (u16*)(w + 41943040);      // [2048,2048] bf16
  u16* Qr   = (u16*)(w + 50331648);      // [BH,S,HD]   bf16
  u16* Kr   = (u16*)(w + 67108864);      // [BH,S,HD]   bf16
  u16* Vr   = (u16*)(w + 83886080);      // [BH,S,HD]   bf16
  u16* Vt   = (u16*)(w + 100663296);     // [BH,HD,S]   bf16
  u16* aO   = (u16*)(w + 117440512);     // [B,S,H]     bf16 (attn out)
  float* out = (float*)d_out;

  cvt5_kernel<<<24576, 256, 0, stream>>>(x, wq, wk, wv, wo, xb, wqkv, wob);

  gemm_bt<1><<<dim3(48, 32), 256, 0, stream>>>(xb, wqkv, nullptr, Qr, Kr, Vr, fc, 4096, 6144, 2048);
  transpose_v<<<dim3(64, 4, 32), dim3(32, 8), 0, stream>>>(Vr, Vt);
  attn_kernel<<<256, 256, 0, stream>>>(Qr, Kr, Vt, aO);
  gemm_bt<0><<<dim3(16, 32), 256, 0, stream>>>(aO, wob, out, nullptr, nullptr, nullptr, nullptr, 4096, 2048, 2048);
}